// Round 4
// baseline (338.206 us; speedup 1.0000x reference)
//
#include <hip/hip_runtime.h>
#include <hip/hip_bf16.h>

typedef __attribute__((ext_vector_type(8))) short short8;     // 8 bf16 (MFMA frag)
typedef __attribute__((ext_vector_type(4))) float f32x4;      // MFMA acc frag
typedef __attribute__((ext_vector_type(8))) unsigned short u16x8;
typedef __attribute__((ext_vector_type(4))) unsigned short u16x4;

#define MFMA16(A, B, C) __builtin_amdgcn_mfma_f32_16x16x32_bf16(A, B, C, 0, 0, 0)

static __device__ __forceinline__ unsigned short f2bf(float f) {
    unsigned int u = __builtin_bit_cast(unsigned int, f);
    u += 0x7FFF + ((u >> 16) & 1);   // RNE
    return (unsigned short)(u >> 16);
}

static __device__ __forceinline__ unsigned int cvt_pk_bf16(float a, float b) {
    unsigned int r;
    asm("v_cvt_pk_bf16_f32 %0, %1, %2" : "=v"(r) : "v"(a), "v"(b));
    return r;
}

// fast GELU: 0.5v(1+tanh(c(v+0.044715v^3))) == v * sigmoid(2c(v+0.044715v^3))
//          = v * rcp(1 + exp2(-(k1*v + k2*v^3)))
static __device__ __forceinline__ float gelu_f(float v) {
    const float k1 = 2.3022077646f;   // 2*log2(e)*sqrt(2/pi)
    const float k2 = 0.1029432207f;   // k1*0.044715
    float t = __builtin_amdgcn_exp2f(-(k1 * v + k2 * v * v * v));
    return v * __builtin_amdgcn_rcpf(1.0f + t);
}

typedef const __attribute__((address_space(1))) unsigned int* gas_t;
typedef __attribute__((address_space(3))) unsigned int* las_t;
static __device__ __forceinline__ void gl_lds16(const void* g, void* l) {
    __builtin_amdgcn_global_load_lds((gas_t)g, (las_t)l, 16, 0, 0);
}

// ---------------------------------------------------------------------------
// Weight transpose + cast: W [K][N] fp32  ->  Wt [N][K] bf16
// ---------------------------------------------------------------------------
__global__ void wtrans(const float* __restrict__ W, unsigned short* __restrict__ Wt,
                       int K, int N) {
    __shared__ float tl[32][33];
    const int n0 = blockIdx.x * 32, k0 = blockIdx.y * 32;
    const int tx = threadIdx.x, ty = threadIdx.y;
#pragma unroll
    for (int i = 0; i < 4; i++)
        tl[ty + 8 * i][tx] = W[(long)(k0 + ty + 8 * i) * N + n0 + tx];
    __syncthreads();
#pragma unroll
    for (int i = 0; i < 4; i++)
        Wt[(long)(n0 + ty + 8 * i) * K + k0 + tx] = f2bf(tl[tx][ty + 8 * i]);
}

// ---------------------------------------------------------------------------
// LayerNorm: fp32 [rows][768] -> bf16 [rows][768].  One wave per row.
// ---------------------------------------------------------------------------
__global__ __launch_bounds__(256)
void ln_fwd(const float* __restrict__ x, const float* __restrict__ gw,
            const float* __restrict__ bw, unsigned short* __restrict__ out) {
    const int row = blockIdx.x * 4 + (threadIdx.x >> 6);
    const int ln = threadIdx.x & 63;
    const float4* xr = (const float4*)(x + (long)row * 768);
    float4 v[3];
    float s = 0.f;
#pragma unroll
    for (int j = 0; j < 3; j++) {
        v[j] = xr[ln + 64 * j];
        s += v[j].x + v[j].y + v[j].z + v[j].w;
    }
#pragma unroll
    for (int off = 32; off >= 1; off >>= 1) s += __shfl_xor(s, off);
    const float mean = s * (1.0f / 768.0f);
    float sq = 0.f;
#pragma unroll
    for (int j = 0; j < 3; j++) {
        float a = v[j].x - mean, b = v[j].y - mean, c = v[j].z - mean, d = v[j].w - mean;
        sq += a * a + b * b + c * c + d * d;
    }
#pragma unroll
    for (int off = 32; off >= 1; off >>= 1) sq += __shfl_xor(sq, off);
    const float rstd = rsqrtf(sq * (1.0f / 768.0f) + 1e-5f);
#pragma unroll
    for (int j = 0; j < 3; j++) {
        const int c = ln + 64 * j;
        float4 gg = ((const float4*)gw)[c];
        float4 bb = ((const float4*)bw)[c];
        u16x4 o;
        o[0] = f2bf((v[j].x - mean) * rstd * gg.x + bb.x);
        o[1] = f2bf((v[j].y - mean) * rstd * gg.y + bb.y);
        o[2] = f2bf((v[j].z - mean) * rstd * gg.z + bb.z);
        o[3] = f2bf((v[j].w - mean) * rstd * gg.w + bb.w);
        *(u16x4*)(out + (long)row * 768 + c * 4) = o;
    }
}

// ---------------------------------------------------------------------------
// GEMM  C[M,N] = A[M,K] (bf16) x Bt[N,K]^T (bf16) + bias, fused epilogues.
// m97 mainloop: 128x128 tile, BK=64, global_load_lds dwordx4 into linear LDS
// (pre-swizzled global source), swizzled ds_read_b128.  1D grid with
// bijective 8-XCD swizzle (all grids %8==0).  M fixed at 8192 -> 64 M-tiles.
// Epilogue: acc -> LDS fp32 st[64][128] (two passes; unions with Al/Bl so
// total LDS stays 32768 B = 5 blocks/CU) -> coalesced 16B fused stores.
// MODE 1: qkv  -> bf16, cols<768 scaled 0.125*log2(e)
// MODE 2: proj -> fp32 out = acc + bias + resid
// MODE 3: fc   -> bf16 out = gelu(acc + bias)
// MODE 4: fc2  -> fp32 out = acc + bias + resid
// ---------------------------------------------------------------------------
template <int MODE>
__global__ __launch_bounds__(256)
void gemm_bt(const unsigned short* __restrict__ A, const unsigned short* __restrict__ Bt,
             const float* __restrict__ bias, const float* __restrict__ resid,
             void* __restrict__ Out, int M, int N, int K) {
    __shared__ char smem[64 * 128 * 4];               // 32768 B: Al+Bl | epilogue st
    unsigned short* Al = (unsigned short*)smem;
    unsigned short* Bl = Al + 128 * 64;
    float* st = (float*)smem;
    const int tid = threadIdx.x;
    const int wv = tid >> 6, ln = tid & 63;
    const int wr = wv >> 1, wc = wv & 1;
    const int g = ln >> 4, r = ln & 15;
    const int lr = ln >> 3, l8 = ln & 7;
    const int sw = l8 ^ lr;                 // staged logical chunk (row&7 == lr)

    // bijective 8-XCD chunk swizzle; nwg % 8 == 0 for all our grids
    const int nwg = (int)gridDim.x;
    int wg = (int)blockIdx.x;
    wg = (wg & 7) * (nwg >> 3) + (wg >> 3);
    const long mbase = (long)(wg & 63) * 128;        // M = 8192 -> 64 M-tiles
    const long nbase = (long)(wg >> 6) * 128;

    f32x4 acc[4][4];
    const f32x4 zero = {0.f, 0.f, 0.f, 0.f};
#pragma unroll
    for (int m = 0; m < 4; m++)
#pragma unroll
        for (int n = 0; n < 4; n++) acc[m][n] = zero;

    const int rx = r & 7;
    for (int k0 = 0; k0 < K; k0 += 64) {
        __syncthreads();
#pragma unroll
        for (int p = 0; p < 4; p++) {
            const int row = p * 32 + wv * 8 + lr;
            gl_lds16(A + (mbase + row) * (long)K + k0 + sw * 8,
                     (char*)Al + (p * 32 + wv * 8) * 128);
            gl_lds16(Bt + (nbase + row) * (long)K + k0 + sw * 8,
                     (char*)Bl + (p * 32 + wv * 8) * 128);
        }
        __syncthreads();
#pragma unroll
        for (int ks = 0; ks < 2; ks++) {
            short8 af[4], bfr[4];
#pragma unroll
            for (int m = 0; m < 4; m++)
                af[m] = *(const short8*)(Al + (wr * 64 + m * 16 + r) * 64 + ((g + 4 * ks) ^ rx) * 8);
#pragma unroll
            for (int n = 0; n < 4; n++)
                bfr[n] = *(const short8*)(Bl + (wc * 64 + n * 16 + r) * 64 + ((g + 4 * ks) ^ rx) * 8);
#pragma unroll
            for (int m = 0; m < 4; m++)
#pragma unroll
                for (int n = 0; n < 4; n++) acc[m][n] = MFMA16(af[m], bfr[n], acc[m][n]);
        }
    }

    // ---- epilogue: two 64-row passes through LDS, coalesced fused stores
    const int tr = tid >> 2, seg = tid & 3;
#pragma unroll 1
    for (int half = 0; half < 2; half++) {
        __syncthreads();
        if (wr == half) {
#pragma unroll
            for (int m = 0; m < 4; m++)
#pragma unroll
                for (int n = 0; n < 4; n++)
#pragma unroll
                    for (int i = 0; i < 4; i++)
                        st[(m * 16 + g * 4 + i) * 128 + wc * 64 + n * 16 + r] = acc[m][n][i];
        }
        __syncthreads();
        const long row = mbase + half * 64 + tr;
        const long cb = nbase + seg * 32;
        if constexpr (MODE == 1 || MODE == 3) {
            const float qs = (MODE == 1 && nbase < 768) ? 0.18033688011112042f : 1.0f;
            unsigned short* op = (unsigned short*)Out + row * N + cb;
#pragma unroll
            for (int u2 = 0; u2 < 4; u2++) {
                float4 a = *(const float4*)(st + tr * 128 + seg * 32 + u2 * 8);
                float4 b = *(const float4*)(st + tr * 128 + seg * 32 + u2 * 8 + 4);
                float4 ba = ((const float4*)bias)[(cb >> 2) + u2 * 2];
                float4 bb = ((const float4*)bias)[(cb >> 2) + u2 * 2 + 1];
                a.x += ba.x; a.y += ba.y; a.z += ba.z; a.w += ba.w;
                b.x += bb.x; b.y += bb.y; b.z += bb.z; b.w += bb.w;
                if constexpr (MODE == 1) {
                    a.x *= qs; a.y *= qs; a.z *= qs; a.w *= qs;
                    b.x *= qs; b.y *= qs; b.z *= qs; b.w *= qs;
                } else {
                    a.x = gelu_f(a.x); a.y = gelu_f(a.y); a.z = gelu_f(a.z); a.w = gelu_f(a.w);
                    b.x = gelu_f(b.x); b.y = gelu_f(b.y); b.z = gelu_f(b.z); b.w = gelu_f(b.w);
                }
                uint4 w;
                w.x = cvt_pk_bf16(a.x, a.y);
                w.y = cvt_pk_bf16(a.z, a.w);
                w.z = cvt_pk_bf16(b.x, b.y);
                w.w = cvt_pk_bf16(b.z, b.w);
                *(uint4*)(op + u2 * 8) = w;
            }
        } else {
            float* op = (float*)Out + row * N + cb;
            const float* rp = resid + row * N + cb;
#pragma unroll
            for (int u = 0; u < 8; u++) {
                float4 a = *(const float4*)(st + tr * 128 + seg * 32 + u * 4);
                float4 ba = ((const float4*)bias)[(cb >> 2) + u];
                float4 rr = ((const float4*)rp)[u];
                a.x += ba.x + rr.x; a.y += ba.y + rr.y;
                a.z += ba.z + rr.z; a.w += ba.w + rr.w;
                ((float4*)op)[u] = a;
            }
        }
    }
}

// ---------------------------------------------------------------------------
// V transpose: qkv[b][t][1536 + h*64 + d] -> vT[bh][d][t]   (bf16, linear)
// ---------------------------------------------------------------------------
__global__ __launch_bounds__(256)
void vtrans(const unsigned short* __restrict__ qkv, unsigned short* __restrict__ vT) {
    const int t0 = blockIdx.x * 64;
    const int bh = blockIdx.y;
    const int b = bh / 12, h = bh % 12;
    __shared__ unsigned short tl[64 * 72];
    const int tid = threadIdx.x;
#pragma unroll
    for (int p = 0; p < 2; p++) {
        int idx = p * 256 + tid;
        int row = idx >> 3, blk = idx & 7;
        int sb = (blk + row) % 9;
        *(u16x8*)(tl + row * 72 + sb * 8) =
            *(const u16x8*)(qkv + ((long)(b * 2048 + t0 + row)) * 2304 + 1536 + h * 64 + blk * 8);
    }
    __syncthreads();
#pragma unroll
    for (int p = 0; p < 2; p++) {
        int idx = p * 256 + tid;
        int d = idx >> 3, tc = (idx & 7) * 8;
        u16x8 v;
#pragma unroll
        for (int j = 0; j < 8; j++) {
            int t = tc + j;
            int sb = ((d >> 3) + t) % 9;
            v[j] = tl[t * 72 + sb * 8 + (d & 7)];
        }
        *(u16x8*)(vT + ((long)(bh * 64 + d)) * 2048 + t0 + tc) = v;
    }
}

// ---------------------------------------------------------------------------
// Flash attention fwd (causal), exp2 domain (q pre-scaled by 0.125*log2e).
// Block = one (b,h) x a PAIR of q-tiles (qt, 31-qt): uniform 33 k-tiles/block.
// ---------------------------------------------------------------------------
__global__ __launch_bounds__(256)
void attn_fwd(const unsigned short* __restrict__ qkv, const unsigned short* __restrict__ vT,
              unsigned short* __restrict__ y) {
    const int pair = blockIdx.x;                 // 0..15
    const int bh = blockIdx.y;
    const int b = bh / 12, h = bh % 12;
    __shared__ unsigned short Kl[64 * 64], Vl[64 * 64], Pl[64 * 72];
    const int tid = threadIdx.x;
    const int wv = tid >> 6, ln = tid & 63;
    const int g = ln >> 4, r = ln & 15;
    const int lr = ln >> 3, l8 = ln & 7;
    const int sw = l8 ^ lr;                      // staging chunk swizzle
    const int rx = r & 7;
    const f32x4 zero = {0.f, 0.f, 0.f, 0.f};

#pragma unroll 1
    for (int qi = 0; qi < 2; qi++) {
        const int qt = qi ? (31 - pair) : pair;
        const int q0 = qt * 64;
        const int q = wv * 16 + r;               // q-local row this lane owns
        const long qoff = ((long)(b * 2048 + q0 + q)) * 2304 + h * 64;
        short8 bq0 = *(const short8*)(qkv + qoff + g * 8);
        short8 bq1 = *(const short8*)(qkv + qoff + 32 + g * 8);

        float mrow = -1e30f, lrow = 0.0f;
        f32x4 oacc[4];
#pragma unroll
        for (int f = 0; f < 4; f++) oacc[f] = zero;

        for (int kt = 0; kt <= qt; ++kt) {
            __syncthreads();
#pragma unroll
            for (int p = 0; p < 2; p++) {
                const int row = wv * 8 + p * 32 + lr;
                gl_lds16(qkv + ((long)(b * 2048 + kt * 64 + row)) * 2304 + 768 + h * 64 + sw * 8,
                         (char*)Kl + (wv * 8 + p * 32) * 128);
                gl_lds16(vT + ((long)(bh * 64 + row)) * 2048 + kt * 64 + sw * 8,
                         (char*)Vl + (wv * 8 + p * 32) * 128);
            }
            __syncthreads();

            f32x4 s[4];
#pragma unroll
            for (int kf = 0; kf < 4; kf++) {
                short8 a0 = *(const short8*)(Kl + (kf * 16 + r) * 64 + (g ^ rx) * 8);
                short8 a1 = *(const short8*)(Kl + (kf * 16 + r) * 64 + ((g + 4) ^ rx) * 8);
                s[kf] = MFMA16(a0, bq0, zero);
                s[kf] = MFMA16(a1, bq1, s[kf]);
            }
            if (kt == qt) {   // diagonal tile: mask k_local > q_local
#pragma unroll
                for (int kf = 0; kf < 4; kf++)
#pragma unroll
                    for (int i = 0; i < 4; i++)
                        if (kf * 16 + g * 4 + i > q) s[kf][i] = -1e30f;
            }
            // ---- online softmax (log2 domain), defer-max
            float tmax = -1e30f;
#pragma unroll
            for (int kf = 0; kf < 4; kf++)
#pragma unroll
                for (int i = 0; i < 4; i++) tmax = fmaxf(tmax, s[kf][i]);
            tmax = fmaxf(tmax, __shfl_xor(tmax, 16));
            tmax = fmaxf(tmax, __shfl_xor(tmax, 32));
            if (__any(tmax > mrow + 6.0f)) {     // rescale only on real growth
                const float mnew = fmaxf(mrow, tmax);
                const float rs = __builtin_amdgcn_exp2f(mrow - mnew);
                lrow *= rs;
#pragma unroll
                for (int f = 0; f < 4; f++) oacc[f] *= rs;
                mrow = mnew;
            }
            float pv[4][4];
            float psum = 0.f;
#pragma unroll
            for (int kf = 0; kf < 4; kf++)
#pragma unroll
                for (int i = 0; i < 4; i++) {
                    pv[kf][i] = __builtin_amdgcn_exp2f(s[kf][i] - mrow);
                    psum += pv[kf][i];
                }
            psum += __shfl_xor(psum, 16);
            psum += __shfl_xor(psum, 32);
            lrow += psum;

            // ---- P^T -> LDS (wave-local), packed via v_cvt_pk_bf16_f32
#pragma unroll
            for (int kf = 0; kf < 4; kf++) {
                uint2 w;
                w.x = cvt_pk_bf16(pv[kf][0], pv[kf][1]);
                w.y = cvt_pk_bf16(pv[kf][2], pv[kf][3]);
                *(uint2*)(Pl + q * 72 + kf * 16 + g * 4) = w;
            }
            short8 pb0 = *(const short8*)(Pl + q * 72 + g * 8);
            short8 pb1 = *(const short8*)(Pl + q * 72 + 32 + g * 8);
#pragma unroll
            for (int f = 0; f < 4; f++) {
                short8 va0 = *(const short8*)(Vl + (f * 16 + r) * 64 + (g ^ rx) * 8);
                short8 va1 = *(const short8*)(Vl + (f * 16 + r) * 64 + ((g + 4) ^ rx) * 8);
                oacc[f] = MFMA16(va0, pb0, oacc[f]);
                oacc[f] = MFMA16(va1, pb1, oacc[f]);
            }
        }

        // ---- epilogue: O^T frags -> LDS (reuse Pl) -> coalesced global
        const float inv = 1.0f / lrow;
#pragma unroll
        for (int f = 0; f < 4; f++) {
            uint2 w;
            w.x = cvt_pk_bf16(oacc[f][0] * inv, oacc[f][1] * inv);
            w.y = cvt_pk_bf16(oacc[f][2] * inv, oacc[f][3] * inv);
            *(uint2*)(Pl + q * 72 + f * 16 + g * 4) = w;
        }
        __syncthreads();
#pragma unroll
        for (int p = 0; p < 2; p++) {
            int idx = p * 256 + tid;
            int row = idx >> 3, cc = (idx & 7) * 8;
            *(u16x8*)(y + ((long)(b * 2048 + q0 + row)) * 768 + h * 64 + cc) =
                *(const u16x8*)(Pl + row * 72 + cc);
        }
    }
}

// ---------------------------------------------------------------------------
extern "C" void kernel_launch(void* const* d_in, const int* in_sizes, int n_in,
                              void* d_out, int out_size, void* d_ws, size_t ws_size,
                              hipStream_t stream) {
    const float* x      = (const float*)d_in[0];
    const float* ln1_g  = (const float*)d_in[1];
    const float* ln1_b  = (const float*)d_in[2];
    const float* W_attn = (const float*)d_in[3];
    const float* b_attn = (const float*)d_in[4];
    const float* W_proj = (const float*)d_in[5];
    const float* b_proj = (const float*)d_in[6];
    const float* ln2_g  = (const float*)d_in[7];
    const float* ln2_b  = (const float*)d_in[8];
    const float* W_fc   = (const float*)d_in[9];
    const float* b_fc   = (const float*)d_in[10];
    const float* W_fc2  = (const float*)d_in[11];
    const float* b_fc2  = (const float*)d_in[12];

    char* ws = (char*)d_ws;
    size_t off = 0;
    auto alloc = [&](size_t bytes) -> char* {
        char* p = ws + off;
        off += (bytes + 255) & ~(size_t)255;
        return p;
    };
    unsigned short* WtA  = (unsigned short*)alloc((size_t)2304 * 768 * 2);
    unsigned short* WtP  = (unsigned short*)alloc((size_t)768 * 768 * 2);
    unsigned short* WtF  = (unsigned short*)alloc((size_t)3072 * 768 * 2);
    unsigned short* WtF2 = (unsigned short*)alloc((size_t)768 * 3072 * 2);
    unsigned short* bigA = (unsigned short*)alloc((size_t)8192 * 3072 * 2); // qkv, then gelu(fc)
    float*          x1   = (float*)alloc((size_t)8192 * 768 * 4);
    unsigned short* bufD = (unsigned short*)alloc((size_t)8192 * 768 * 2);  // h_ln / y / h_ln2
    unsigned short* vT   = (unsigned short*)alloc((size_t)48 * 64 * 2048 * 2);

    // weights -> bf16 transposed
    wtrans<<<dim3(72, 24), dim3(32, 8), 0, stream>>>(W_attn, WtA, 768, 2304);
    wtrans<<<dim3(24, 24), dim3(32, 8), 0, stream>>>(W_proj, WtP, 768, 768);
    wtrans<<<dim3(96, 24), dim3(32, 8), 0, stream>>>(W_fc, WtF, 768, 3072);
    wtrans<<<dim3(24, 96), dim3(32, 8), 0, stream>>>(W_fc2, WtF2, 3072, 768);
    // LN1: x -> bufD (bf16)
    ln_fwd<<<2048, 256, 0, stream>>>(x, ln1_g, ln1_b, bufD);
    // QKV: bufD @ WtA^T -> bigA (bf16, q scaled 0.125*log2e for exp2-domain softmax)
    gemm_bt<1><<<64 * 18, 256, 0, stream>>>(bufD, WtA, b_attn, nullptr, bigA, 8192, 2304, 768);
    // V transpose
    vtrans<<<dim3(32, 48), 256, 0, stream>>>(bigA, vT);
    // attention -> bufD (= y, bf16); paired q-tiles for uniform work
    attn_fwd<<<dim3(16, 48), 256, 0, stream>>>(bigA, vT, bufD);
    // proj: y @ WtP^T + b + x -> x1 (fp32)
    gemm_bt<2><<<64 * 6, 256, 0, stream>>>(bufD, WtP, b_proj, x, x1, 8192, 768, 768);
    // LN2: x1 -> bufD (bf16)
    ln_fwd<<<2048, 256, 0, stream>>>(x1, ln2_g, ln2_b, bufD);
    // FC + GELU: bufD @ WtF^T -> bigA (bf16)
    gemm_bt<3><<<64 * 24, 256, 0, stream>>>(bufD, WtF, b_fc, nullptr, bigA, 8192, 3072, 768);
    // FC2: bigA @ WtF2^T + b + x1 -> d_out (fp32)
    gemm_bt<4><<<64 * 6, 256, 0, stream>>>(bigA, WtF2, b_fc2, x1, (float*)d_out, 8192, 768, 3072);
}

// Round 5
// 298.832 us; speedup vs baseline: 1.1318x; 1.1318x over previous
//
#include <hip/hip_runtime.h>
#include <hip/hip_bf16.h>

typedef __attribute__((ext_vector_type(8))) short short8;     // 8 bf16 (MFMA frag)
typedef __attribute__((ext_vector_type(4))) float f32x4;      // MFMA acc frag
typedef __attribute__((ext_vector_type(8))) unsigned short u16x8;
typedef __attribute__((ext_vector_type(4))) unsigned short u16x4;

#define MFMA16(A, B, C) __builtin_amdgcn_mfma_f32_16x16x32_bf16(A, B, C, 0, 0, 0)

static __device__ __forceinline__ unsigned short f2bf(float f) {
    unsigned int u = __builtin_bit_cast(unsigned int, f);
    u += 0x7FFF + ((u >> 16) & 1);   // RNE
    return (unsigned short)(u >> 16);
}

static __device__ __forceinline__ unsigned int cvt_pk_bf16(float a, float b) {
    unsigned int r;
    asm("v_cvt_pk_bf16_f32 %0, %1, %2" : "=v"(r) : "v"(a), "v"(b));
    return r;
}

// fast GELU: 0.5v(1+tanh(c(v+0.044715v^3))) == v * sigmoid(2c(v+0.044715v^3))
//          = v * rcp(1 + exp2(-(k1*v + k2*v^3)))
static __device__ __forceinline__ float gelu_f(float v) {
    const float k1 = 2.3022077646f;   // 2*log2(e)*sqrt(2/pi)
    const float k2 = 0.1029432207f;   // k1*0.044715
    float t = __builtin_amdgcn_exp2f(-(k1 * v + k2 * v * v * v));
    return v * __builtin_amdgcn_rcpf(1.0f + t);
}

typedef const __attribute__((address_space(1))) unsigned int* gas_t;
typedef __attribute__((address_space(3))) unsigned int* las_t;
static __device__ __forceinline__ void gl_lds16(const void* g, void* l) {
    __builtin_amdgcn_global_load_lds((gas_t)g, (las_t)l, 16, 0, 0);
}

// ---------------------------------------------------------------------------
// Weight transpose + cast: W [K][N] fp32  ->  Wt [N][K] bf16
// ---------------------------------------------------------------------------
__global__ void wtrans(const float* __restrict__ W, unsigned short* __restrict__ Wt,
                       int K, int N) {
    __shared__ float tl[32][33];
    const int n0 = blockIdx.x * 32, k0 = blockIdx.y * 32;
    const int tx = threadIdx.x, ty = threadIdx.y;
#pragma unroll
    for (int i = 0; i < 4; i++)
        tl[ty + 8 * i][tx] = W[(long)(k0 + ty + 8 * i) * N + n0 + tx];
    __syncthreads();
#pragma unroll
    for (int i = 0; i < 4; i++)
        Wt[(long)(n0 + ty + 8 * i) * K + k0 + tx] = f2bf(tl[tx][ty + 8 * i]);
}

// ---------------------------------------------------------------------------
// LayerNorm: fp32 [rows][768] -> bf16 [rows][768].  One wave per row.
// ---------------------------------------------------------------------------
__global__ __launch_bounds__(256)
void ln_fwd(const float* __restrict__ x, const float* __restrict__ gw,
            const float* __restrict__ bw, unsigned short* __restrict__ out) {
    const int row = blockIdx.x * 4 + (threadIdx.x >> 6);
    const int ln = threadIdx.x & 63;
    const float4* xr = (const float4*)(x + (long)row * 768);
    float4 v[3];
    float s = 0.f;
#pragma unroll
    for (int j = 0; j < 3; j++) {
        v[j] = xr[ln + 64 * j];
        s += v[j].x + v[j].y + v[j].z + v[j].w;
    }
#pragma unroll
    for (int off = 32; off >= 1; off >>= 1) s += __shfl_xor(s, off);
    const float mean = s * (1.0f / 768.0f);
    float sq = 0.f;
#pragma unroll
    for (int j = 0; j < 3; j++) {
        float a = v[j].x - mean, b = v[j].y - mean, c = v[j].z - mean, d = v[j].w - mean;
        sq += a * a + b * b + c * c + d * d;
    }
#pragma unroll
    for (int off = 32; off >= 1; off >>= 1) sq += __shfl_xor(sq, off);
    const float rstd = rsqrtf(sq * (1.0f / 768.0f) + 1e-5f);
#pragma unroll
    for (int j = 0; j < 3; j++) {
        const int c = ln + 64 * j;
        float4 gg = ((const float4*)gw)[c];
        float4 bb = ((const float4*)bw)[c];
        u16x4 o;
        o[0] = f2bf((v[j].x - mean) * rstd * gg.x + bb.x);
        o[1] = f2bf((v[j].y - mean) * rstd * gg.y + bb.y);
        o[2] = f2bf((v[j].z - mean) * rstd * gg.z + bb.z);
        o[3] = f2bf((v[j].w - mean) * rstd * gg.w + bb.w);
        *(u16x4*)(out + (long)row * 768 + c * 4) = o;
    }
}

// ---------------------------------------------------------------------------
// GEMM  C[M,N] = A[M,K] (bf16) x Bt[N,K]^T (bf16) + bias, fused epilogues.
// m97 mainloop: 128xBN tile, BK=64, global_load_lds dwordx4 into linear LDS
// (pre-swizzled global source), swizzled ds_read_b128.  2D grid, m-fastest
// (default round-robin dispatch = XCD-optimal A partitioning; measured r4:
// chunked swizzle tripled FETCH).  BN=128: 2x2 waves of 64x64.  BN=64 (for
// narrow N=768 GEMMs -> 768 blocks = 3/CU): 2x2 waves of 64x32.
// Epilogue: acc -> LDS fp32 staging -> coalesced 16B fused stores.
// MODE 1: qkv  -> bf16, cols<768 scaled 0.125*log2(e)    [BN=128]
// MODE 2: proj -> fp32 out = acc + bias + resid          [BN=64]
// MODE 3: fc   -> bf16 out = gelu(acc + bias)            [BN=128]
// MODE 4: fc2  -> fp32 out = acc + bias + resid          [BN=64]
// ---------------------------------------------------------------------------
template <int MODE, int BN>
__global__ __launch_bounds__(256)
void gemm_bt(const unsigned short* __restrict__ A, const unsigned short* __restrict__ Bt,
             const float* __restrict__ bias, const float* __restrict__ resid,
             void* __restrict__ Out, int M, int N, int K) {
    constexpr int N_FR = BN / 32;                     // n-frags per wave (2x2 waves)
    constexpr int STN = (BN == 128) ? 128 : 68;       // epilogue staging stride (fp32)
    __shared__ char smem[(128 + BN) * 64 * 2];        // Al+Bl | epilogue st (union)
    unsigned short* Al = (unsigned short*)smem;
    unsigned short* Bl = Al + 128 * 64;
    float* st = (float*)smem;
    const int tid = threadIdx.x;
    const int wv = tid >> 6, ln = tid & 63;
    const int wr = wv >> 1, wc = wv & 1;
    const int g = ln >> 4, r = ln & 15;
    const int lr = ln >> 3, l8 = ln & 7;
    const int sw = l8 ^ lr;                 // staged logical chunk (row&7 == lr)
    const long mbase = (long)blockIdx.x * 128;
    const long nbase = (long)blockIdx.y * BN;

    f32x4 acc[4][N_FR];
    const f32x4 zero = {0.f, 0.f, 0.f, 0.f};
#pragma unroll
    for (int m = 0; m < 4; m++)
#pragma unroll
        for (int n = 0; n < N_FR; n++) acc[m][n] = zero;

    const int rx = r & 7;
    for (int k0 = 0; k0 < K; k0 += 64) {
        __syncthreads();
#pragma unroll
        for (int p = 0; p < 4; p++) {
            const int row = p * 32 + wv * 8 + lr;
            gl_lds16(A + (mbase + row) * (long)K + k0 + sw * 8,
                     (char*)Al + (p * 32 + wv * 8) * 128);
        }
#pragma unroll
        for (int p = 0; p < BN / 32; p++) {
            const int row = p * 32 + wv * 8 + lr;
            gl_lds16(Bt + (nbase + row) * (long)K + k0 + sw * 8,
                     (char*)Bl + (p * 32 + wv * 8) * 128);
        }
        __syncthreads();
#pragma unroll
        for (int ks = 0; ks < 2; ks++) {
            short8 af[4], bfr[N_FR];
#pragma unroll
            for (int m = 0; m < 4; m++)
                af[m] = *(const short8*)(Al + (wr * 64 + m * 16 + r) * 64 + ((g + 4 * ks) ^ rx) * 8);
#pragma unroll
            for (int n = 0; n < N_FR; n++)
                bfr[n] = *(const short8*)(Bl + (wc * (BN / 2) + n * 16 + r) * 64 + ((g + 4 * ks) ^ rx) * 8);
#pragma unroll
            for (int m = 0; m < 4; m++)
#pragma unroll
                for (int n = 0; n < N_FR; n++) acc[m][n] = MFMA16(af[m], bfr[n], acc[m][n]);
        }
    }

    // ---- epilogue: two 64-row passes through LDS, coalesced fused stores
    const int tr = tid >> 2, seg = tid & 3;
#pragma unroll 1
    for (int half = 0; half < 2; half++) {
        __syncthreads();
        if (wr == half) {
#pragma unroll
            for (int m = 0; m < 4; m++)
#pragma unroll
                for (int n = 0; n < N_FR; n++)
#pragma unroll
                    for (int i = 0; i < 4; i++)
                        st[(m * 16 + g * 4 + i) * STN + wc * (BN / 2) + n * 16 + r] = acc[m][n][i];
        }
        __syncthreads();
        const long row = mbase + half * 64 + tr;
        if constexpr (BN == 128) {
            const long cb = nbase + seg * 32;
            if constexpr (MODE == 1 || MODE == 3) {
                const float qs = (MODE == 1 && nbase < 768) ? 0.18033688011112042f : 1.0f;
                unsigned short* op = (unsigned short*)Out + row * N + cb;
#pragma unroll
                for (int u2 = 0; u2 < 4; u2++) {
                    float4 a = *(const float4*)(st + tr * STN + seg * 32 + u2 * 8);
                    float4 b = *(const float4*)(st + tr * STN + seg * 32 + u2 * 8 + 4);
                    float4 ba = ((const float4*)bias)[(cb >> 2) + u2 * 2];
                    float4 bb = ((const float4*)bias)[(cb >> 2) + u2 * 2 + 1];
                    a.x += ba.x; a.y += ba.y; a.z += ba.z; a.w += ba.w;
                    b.x += bb.x; b.y += bb.y; b.z += bb.z; b.w += bb.w;
                    if constexpr (MODE == 1) {
                        a.x *= qs; a.y *= qs; a.z *= qs; a.w *= qs;
                        b.x *= qs; b.y *= qs; b.z *= qs; b.w *= qs;
                    } else {
                        a.x = gelu_f(a.x); a.y = gelu_f(a.y); a.z = gelu_f(a.z); a.w = gelu_f(a.w);
                        b.x = gelu_f(b.x); b.y = gelu_f(b.y); b.z = gelu_f(b.z); b.w = gelu_f(b.w);
                    }
                    uint4 w;
                    w.x = cvt_pk_bf16(a.x, a.y);
                    w.y = cvt_pk_bf16(a.z, a.w);
                    w.z = cvt_pk_bf16(b.x, b.y);
                    w.w = cvt_pk_bf16(b.z, b.w);
                    *(uint4*)(op + u2 * 8) = w;
                }
            } else {
                float* op = (float*)Out + row * N + cb;
                const float* rp = resid + row * N + cb;
#pragma unroll
                for (int u = 0; u < 8; u++) {
                    float4 a = *(const float4*)(st + tr * STN + seg * 32 + u * 4);
                    float4 ba = ((const float4*)bias)[(cb >> 2) + u];
                    float4 rr = ((const float4*)rp)[u];
                    a.x += ba.x + rr.x; a.y += ba.y + rr.y;
                    a.z += ba.z + rr.z; a.w += ba.w + rr.w;
                    ((float4*)op)[u] = a;
                }
            }
        } else {
            // BN == 64: only the fp32 + resid modes (proj / fc2)
            const long cb = nbase + seg * 16;
            float* op = (float*)Out + row * N + cb;
            const float* rp = resid + row * N + cb;
#pragma unroll
            for (int u = 0; u < 4; u++) {
                float4 a = *(const float4*)(st + tr * STN + seg * 16 + u * 4);
                float4 ba = ((const float4*)bias)[(cb >> 2) + u];
                float4 rr = ((const float4*)rp)[u];
                a.x += ba.x + rr.x; a.y += ba.y + rr.y;
                a.z += ba.z + rr.z; a.w += ba.w + rr.w;
                ((float4*)op)[u] = a;
            }
        }
    }
}

// ---------------------------------------------------------------------------
// V transpose: qkv[b][t][1536 + h*64 + d] -> vT[bh][d][t]   (bf16, linear)
// ---------------------------------------------------------------------------
__global__ __launch_bounds__(256)
void vtrans(const unsigned short* __restrict__ qkv, unsigned short* __restrict__ vT) {
    const int t0 = blockIdx.x * 64;
    const int bh = blockIdx.y;
    const int b = bh / 12, h = bh % 12;
    __shared__ unsigned short tl[64 * 72];
    const int tid = threadIdx.x;
#pragma unroll
    for (int p = 0; p < 2; p++) {
        int idx = p * 256 + tid;
        int row = idx >> 3, blk = idx & 7;
        int sb = (blk + row) % 9;
        *(u16x8*)(tl + row * 72 + sb * 8) =
            *(const u16x8*)(qkv + ((long)(b * 2048 + t0 + row)) * 2304 + 1536 + h * 64 + blk * 8);
    }
    __syncthreads();
#pragma unroll
    for (int p = 0; p < 2; p++) {
        int idx = p * 256 + tid;
        int d = idx >> 3, tc = (idx & 7) * 8;
        u16x8 v;
#pragma unroll
        for (int j = 0; j < 8; j++) {
            int t = tc + j;
            int sb = ((d >> 3) + t) % 9;
            v[j] = tl[t * 72 + sb * 8 + (d & 7)];
        }
        *(u16x8*)(vT + ((long)(bh * 64 + d)) * 2048 + t0 + tc) = v;
    }
}

// ---------------------------------------------------------------------------
// Flash attention fwd (causal), exp2 domain (q pre-scaled by 0.125*log2e).
// Block = one (b,h) x a PAIR of q-tiles (qt, 31-qt): uniform 33 k-tiles/block.
// ---------------------------------------------------------------------------
__global__ __launch_bounds__(256)
void attn_fwd(const unsigned short* __restrict__ qkv, const unsigned short* __restrict__ vT,
              unsigned short* __restrict__ y) {
    const int pair = blockIdx.x;                 // 0..15
    const int bh = blockIdx.y;
    const int b = bh / 12, h = bh % 12;
    __shared__ unsigned short Kl[64 * 64], Vl[64 * 64], Pl[64 * 72];
    const int tid = threadIdx.x;
    const int wv = tid >> 6, ln = tid & 63;
    const int g = ln >> 4, r = ln & 15;
    const int lr = ln >> 3, l8 = ln & 7;
    const int sw = l8 ^ lr;                      // staging chunk swizzle
    const int rx = r & 7;
    const f32x4 zero = {0.f, 0.f, 0.f, 0.f};

#pragma unroll 1
    for (int qi = 0; qi < 2; qi++) {
        const int qt = qi ? (31 - pair) : pair;
        const int q0 = qt * 64;
        const int q = wv * 16 + r;               // q-local row this lane owns
        const long qoff = ((long)(b * 2048 + q0 + q)) * 2304 + h * 64;
        short8 bq0 = *(const short8*)(qkv + qoff + g * 8);
        short8 bq1 = *(const short8*)(qkv + qoff + 32 + g * 8);

        float mrow = -1e30f, lrow = 0.0f;
        f32x4 oacc[4];
#pragma unroll
        for (int f = 0; f < 4; f++) oacc[f] = zero;

        for (int kt = 0; kt <= qt; ++kt) {
            __syncthreads();
#pragma unroll
            for (int p = 0; p < 2; p++) {
                const int row = wv * 8 + p * 32 + lr;
                gl_lds16(qkv + ((long)(b * 2048 + kt * 64 + row)) * 2304 + 768 + h * 64 + sw * 8,
                         (char*)Kl + (wv * 8 + p * 32) * 128);
                gl_lds16(vT + ((long)(bh * 64 + row)) * 2048 + kt * 64 + sw * 8,
                         (char*)Vl + (wv * 8 + p * 32) * 128);
            }
            __syncthreads();

            f32x4 s[4];
#pragma unroll
            for (int kf = 0; kf < 4; kf++) {
                short8 a0 = *(const short8*)(Kl + (kf * 16 + r) * 64 + (g ^ rx) * 8);
                short8 a1 = *(const short8*)(Kl + (kf * 16 + r) * 64 + ((g + 4) ^ rx) * 8);
                s[kf] = MFMA16(a0, bq0, zero);
                s[kf] = MFMA16(a1, bq1, s[kf]);
            }
            if (kt == qt) {   // diagonal tile: mask k_local > q_local
#pragma unroll
                for (int kf = 0; kf < 4; kf++)
#pragma unroll
                    for (int i = 0; i < 4; i++)
                        if (kf * 16 + g * 4 + i > q) s[kf][i] = -1e30f;
            }
            // ---- online softmax (log2 domain), defer-max
            float tmax = -1e30f;
#pragma unroll
            for (int kf = 0; kf < 4; kf++)
#pragma unroll
                for (int i = 0; i < 4; i++) tmax = fmaxf(tmax, s[kf][i]);
            tmax = fmaxf(tmax, __shfl_xor(tmax, 16));
            tmax = fmaxf(tmax, __shfl_xor(tmax, 32));
            if (__any(tmax > mrow + 6.0f)) {     // rescale only on real growth
                const float mnew = fmaxf(mrow, tmax);
                const float rs = __builtin_amdgcn_exp2f(mrow - mnew);
                lrow *= rs;
#pragma unroll
                for (int f = 0; f < 4; f++) oacc[f] *= rs;
                mrow = mnew;
            }
            float pv[4][4];
            float psum = 0.f;
#pragma unroll
            for (int kf = 0; kf < 4; kf++)
#pragma unroll
                for (int i = 0; i < 4; i++) {
                    pv[kf][i] = __builtin_amdgcn_exp2f(s[kf][i] - mrow);
                    psum += pv[kf][i];
                }
            psum += __shfl_xor(psum, 16);
            psum += __shfl_xor(psum, 32);
            lrow += psum;

            // ---- P^T -> LDS (wave-local), packed via v_cvt_pk_bf16_f32
#pragma unroll
            for (int kf = 0; kf < 4; kf++) {
                uint2 w;
                w.x = cvt_pk_bf16(pv[kf][0], pv[kf][1]);
                w.y = cvt_pk_bf16(pv[kf][2], pv[kf][3]);
                *(uint2*)(Pl + q * 72 + kf * 16 + g * 4) = w;
            }
            short8 pb0 = *(const short8*)(Pl + q * 72 + g * 8);
            short8 pb1 = *(const short8*)(Pl + q * 72 + 32 + g * 8);
#pragma unroll
            for (int f = 0; f < 4; f++) {
                short8 va0 = *(const short8*)(Vl + (f * 16 + r) * 64 + (g ^ rx) * 8);
                short8 va1 = *(const short8*)(Vl + (f * 16 + r) * 64 + ((g + 4) ^ rx) * 8);
                oacc[f] = MFMA16(va0, pb0, oacc[f]);
                oacc[f] = MFMA16(va1, pb1, oacc[f]);
            }
        }

        // ---- epilogue: O^T frags -> LDS (reuse Pl) -> coalesced global
        const float inv = 1.0f / lrow;
#pragma unroll
        for (int f = 0; f < 4; f++) {
            uint2 w;
            w.x = cvt_pk_bf16(oacc[f][0] * inv, oacc[f][1] * inv);
            w.y = cvt_pk_bf16(oacc[f][2] * inv, oacc[f][3] * inv);
            *(uint2*)(Pl + q * 72 + f * 16 + g * 4) = w;
        }
        __syncthreads();
#pragma unroll
        for (int p = 0; p < 2; p++) {
            int idx = p * 256 + tid;
            int row = idx >> 3, cc = (idx & 7) * 8;
            *(u16x8*)(y + ((long)(b * 2048 + q0 + row)) * 768 + h * 64 + cc) =
                *(const u16x8*)(Pl + row * 72 + cc);
        }
    }
}

// ---------------------------------------------------------------------------
extern "C" void kernel_launch(void* const* d_in, const int* in_sizes, int n_in,
                              void* d_out, int out_size, void* d_ws, size_t ws_size,
                              hipStream_t stream) {
    const float* x      = (const float*)d_in[0];
    const float* ln1_g  = (const float*)d_in[1];
    const float* ln1_b  = (const float*)d_in[2];
    const float* W_attn = (const float*)d_in[3];
    const float* b_attn = (const float*)d_in[4];
    const float* W_proj = (const float*)d_in[5];
    const float* b_proj = (const float*)d_in[6];
    const float* ln2_g  = (const float*)d_in[7];
    const float* ln2_b  = (const float*)d_in[8];
    const float* W_fc   = (const float*)d_in[9];
    const float* b_fc   = (const float*)d_in[10];
    const float* W_fc2  = (const float*)d_in[11];
    const float* b_fc2  = (const float*)d_in[12];

    char* ws = (char*)d_ws;
    size_t off = 0;
    auto alloc = [&](size_t bytes) -> char* {
        char* p = ws + off;
        off += (bytes + 255) & ~(size_t)255;
        return p;
    };
    unsigned short* WtA  = (unsigned short*)alloc((size_t)2304 * 768 * 2);
    unsigned short* WtP  = (unsigned short*)alloc((size_t)768 * 768 * 2);
    unsigned short* WtF  = (unsigned short*)alloc((size_t)3072 * 768 * 2);
    unsigned short* WtF2 = (unsigned short*)alloc((size_t)768 * 3072 * 2);
    unsigned short* bigA = (unsigned short*)alloc((size_t)8192 * 3072 * 2); // qkv, then gelu(fc)
    float*          x1   = (float*)alloc((size_t)8192 * 768 * 4);
    unsigned short* bufD = (unsigned short*)alloc((size_t)8192 * 768 * 2);  // h_ln / y / h_ln2
    unsigned short* vT   = (unsigned short*)alloc((size_t)48 * 64 * 2048 * 2);

    // weights -> bf16 transposed
    wtrans<<<dim3(72, 24), dim3(32, 8), 0, stream>>>(W_attn, WtA, 768, 2304);
    wtrans<<<dim3(24, 24), dim3(32, 8), 0, stream>>>(W_proj, WtP, 768, 768);
    wtrans<<<dim3(96, 24), dim3(32, 8), 0, stream>>>(W_fc, WtF, 768, 3072);
    wtrans<<<dim3(24, 96), dim3(32, 8), 0, stream>>>(W_fc2, WtF2, 3072, 768);
    // LN1: x -> bufD (bf16)
    ln_fwd<<<2048, 256, 0, stream>>>(x, ln1_g, ln1_b, bufD);
    // QKV: bufD @ WtA^T -> bigA (bf16, q scaled 0.125*log2e for exp2-domain softmax)
    gemm_bt<1, 128><<<dim3(64, 18), 256, 0, stream>>>(bufD, WtA, b_attn, nullptr, bigA, 8192, 2304, 768);
    // V transpose
    vtrans<<<dim3(32, 48), 256, 0, stream>>>(bigA, vT);
    // attention -> bufD (= y, bf16); paired q-tiles for uniform work
    attn_fwd<<<dim3(16, 48), 256, 0, stream>>>(bigA, vT, bufD);
    // proj: y @ WtP^T + b + x -> x1 (fp32)   [BN=64 -> 768 blocks]
    gemm_bt<2, 64><<<dim3(64, 12), 256, 0, stream>>>(bufD, WtP, b_proj, x, x1, 8192, 768, 768);
    // LN2: x1 -> bufD (bf16)
    ln_fwd<<<2048, 256, 0, stream>>>(x1, ln2_g, ln2_b, bufD);
    // FC + GELU: bufD @ WtF^T -> bigA (bf16)
    gemm_bt<3, 128><<<dim3(64, 24), 256, 0, stream>>>(bufD, WtF, b_fc, nullptr, bigA, 8192, 3072, 768);
    // FC2: bigA @ WtF2^T + b + x1 -> d_out (fp32)   [BN=64 -> 768 blocks]
    gemm_bt<4, 64><<<dim3(64, 12), 256, 0, stream>>>(bigA, WtF2, b_fc2, x1, (float*)d_out, 8192, 768, 3072);
}

// Round 6
// 292.290 us; speedup vs baseline: 1.1571x; 1.0224x over previous
//
#include <hip/hip_runtime.h>
#include <hip/hip_bf16.h>

typedef __attribute__((ext_vector_type(8))) short short8;     // 8 bf16 (MFMA frag)
typedef __attribute__((ext_vector_type(4))) float f32x4;      // MFMA acc frag
typedef __attribute__((ext_vector_type(8))) unsigned short u16x8;
typedef __attribute__((ext_vector_type(4))) unsigned short u16x4;

#define MFMA16(A, B, C) __builtin_amdgcn_mfma_f32_16x16x32_bf16(A, B, C, 0, 0, 0)

static __device__ __forceinline__ unsigned short f2bf(float f) {
    unsigned int u = __builtin_bit_cast(unsigned int, f);
    u += 0x7FFF + ((u >> 16) & 1);   // RNE
    return (unsigned short)(u >> 16);
}

static __device__ __forceinline__ unsigned int cvt_pk_bf16(float a, float b) {
    unsigned int r;
    asm("v_cvt_pk_bf16_f32 %0, %1, %2" : "=v"(r) : "v"(a), "v"(b));
    return r;
}

// fast GELU: 0.5v(1+tanh(c(v+0.044715v^3))) == v * rcp(1 + exp2(-(k1*v + k2*v^3)))
static __device__ __forceinline__ float gelu_f(float v) {
    const float k1 = 2.3022077646f;   // 2*log2(e)*sqrt(2/pi)
    const float k2 = 0.1029432207f;   // k1*0.044715
    float t = __builtin_amdgcn_exp2f(-(k1 * v + k2 * v * v * v));
    return v * __builtin_amdgcn_rcpf(1.0f + t);
}

typedef const __attribute__((address_space(1))) unsigned int* gas_t;
typedef __attribute__((address_space(3))) unsigned int* las_t;
static __device__ __forceinline__ void gl_lds16(const void* g, void* l) {
    __builtin_amdgcn_global_load_lds((gas_t)g, (las_t)l, 16, 0, 0);
}

// ---------------------------------------------------------------------------
// Weight transpose + cast: W [K][N] fp32  ->  Wt [N][K] bf16
// ---------------------------------------------------------------------------
__global__ void wtrans(const float* __restrict__ W, unsigned short* __restrict__ Wt,
                       int K, int N) {
    __shared__ float tl[32][33];
    const int n0 = blockIdx.x * 32, k0 = blockIdx.y * 32;
    const int tx = threadIdx.x, ty = threadIdx.y;
#pragma unroll
    for (int i = 0; i < 4; i++)
        tl[ty + 8 * i][tx] = W[(long)(k0 + ty + 8 * i) * N + n0 + tx];
    __syncthreads();
#pragma unroll
    for (int i = 0; i < 4; i++)
        Wt[(long)(n0 + ty + 8 * i) * K + k0 + tx] = f2bf(tl[tx][ty + 8 * i]);
}

// ---------------------------------------------------------------------------
// LayerNorm: fp32 [rows][768] -> bf16 [rows][768].  One wave per row.
// ---------------------------------------------------------------------------
__global__ __launch_bounds__(256)
void ln_fwd(const float* __restrict__ x, const float* __restrict__ gw,
            const float* __restrict__ bw, unsigned short* __restrict__ out) {
    const int row = blockIdx.x * 4 + (threadIdx.x >> 6);
    const int ln = threadIdx.x & 63;
    const float4* xr = (const float4*)(x + (long)row * 768);
    float4 v[3];
    float s = 0.f;
#pragma unroll
    for (int j = 0; j < 3; j++) {
        v[j] = xr[ln + 64 * j];
        s += v[j].x + v[j].y + v[j].z + v[j].w;
    }
#pragma unroll
    for (int off = 32; off >= 1; off >>= 1) s += __shfl_xor(s, off);
    const float mean = s * (1.0f / 768.0f);
    float sq = 0.f;
#pragma unroll
    for (int j = 0; j < 3; j++) {
        float a = v[j].x - mean, b = v[j].y - mean, c = v[j].z - mean, d = v[j].w - mean;
        sq += a * a + b * b + c * c + d * d;
    }
#pragma unroll
    for (int off = 32; off >= 1; off >>= 1) sq += __shfl_xor(sq, off);
    const float rstd = rsqrtf(sq * (1.0f / 768.0f) + 1e-5f);
#pragma unroll
    for (int j = 0; j < 3; j++) {
        const int c = ln + 64 * j;
        float4 gg = ((const float4*)gw)[c];
        float4 bb = ((const float4*)bw)[c];
        u16x4 o;
        o[0] = f2bf((v[j].x - mean) * rstd * gg.x + bb.x);
        o[1] = f2bf((v[j].y - mean) * rstd * gg.y + bb.y);
        o[2] = f2bf((v[j].z - mean) * rstd * gg.z + bb.z);
        o[3] = f2bf((v[j].w - mean) * rstd * gg.w + bb.w);
        *(u16x4*)(out + (long)row * 768 + c * 4) = o;
    }
}

// ---------------------------------------------------------------------------
// GEMM  C[M,N] = A[M,K] (bf16) x Bt[N,K]^T (bf16) + bias, fused epilogues.
// 2-phase pipelined mainloop: 128xBN tile, BK=32, DOUBLE-buffered LDS.
// Per iter: issue global_load_lds for tile t+1 into buf^1, then ds_read+MFMA
// tile t from buf, then one __syncthreads() (vmcnt(0) drain covered by the
// compute).  Chunk-XOR swizzle (4 chunks of 16B per 64B row): LDS chunk c of
// row p holds global chunk c^(p&3); staged via pre-swizzled global source.
// LDS: 2x(128+BN)x32x2B (<=32KB) unioned with the fp32 epilogue staging
// (stride 132 for BN=128: conflict-free reads, measured r3 98K vs r5 3.5M).
// VGPR=92 caps residency at 4 blocks/CU, so 33.8KB LDS is free.
// MODE 1: qkv  -> bf16, cols<768 scaled 0.125*log2(e)    [BN=128]
// MODE 2: proj -> fp32 out = acc + bias + resid          [BN=64]
// MODE 3: fc   -> bf16 out = gelu(acc + bias)            [BN=128]
// MODE 4: fc2  -> fp32 out = acc + bias + resid          [BN=64]
// ---------------------------------------------------------------------------
template <int MODE, int BN>
__global__ __launch_bounds__(256)
void gemm_bt(const unsigned short* __restrict__ A, const unsigned short* __restrict__ Bt,
             const float* __restrict__ bias, const float* __restrict__ resid,
             void* __restrict__ Out, int M, int N, int K) {
    constexpr int NW = BN / 32;                        // n-frags per wave (2x2 waves)
    constexpr int BUF = (128 + BN) * 32;               // u16 elems per K-tile buffer
    constexpr int STN = (BN == 128) ? 132 : 68;        // epilogue staging stride (fp32)
    constexpr int BYTES_MAIN = 2 * BUF * 2;
    constexpr int BYTES_ST = 64 * STN * 4;
    constexpr int BYTES = BYTES_MAIN > BYTES_ST ? BYTES_MAIN : BYTES_ST;
    __shared__ char smem[BYTES];
    unsigned short* ubase = (unsigned short*)smem;
    float* st = (float*)smem;

    const int tid = threadIdx.x;
    const int wv = tid >> 6, ln = tid & 63;
    const int wr = wv >> 1, wc = wv & 1;
    const int g = ln >> 4, r = ln & 15;
    const int sr = ln >> 2, sc = ln & 3;               // staging row-in-16 / chunk
    const int ssw = sc ^ (sr & 3);                     // pre-swizzled source chunk
    const long mbase = (long)blockIdx.x * 128;
    const long nbase = (long)blockIdx.y * BN;

    f32x4 acc[4][NW];
    const f32x4 zero = {0.f, 0.f, 0.f, 0.f};
#pragma unroll
    for (int m = 0; m < 4; m++)
#pragma unroll
        for (int n = 0; n < NW; n++) acc[m][n] = zero;

    const int nt = K >> 5;
    // ---- prologue: stage tile 0 into buf 0
#pragma unroll
    for (int p = 0; p < 2; p++)
        gl_lds16(A + (mbase + p * 64 + wv * 16 + sr) * (long)K + ssw * 8,
                 ubase + (p * 64 + wv * 16) * 32);
#pragma unroll
    for (int p = 0; p < BN / 64; p++)
        gl_lds16(Bt + (nbase + p * 64 + wv * 16 + sr) * (long)K + ssw * 8,
                 ubase + 128 * 32 + (p * 64 + wv * 16) * 32);
    __syncthreads();

    const int cxr = r & 3;
    for (int t = 0; t < nt; t++) {
        const unsigned short* cbuf = ubase + (t & 1) * BUF;
        if (t + 1 < nt) {                              // issue next-tile loads first
            unsigned short* nbuf = ubase + ((t + 1) & 1) * BUF;
            const long k0 = (long)(t + 1) << 5;
#pragma unroll
            for (int p = 0; p < 2; p++)
                gl_lds16(A + (mbase + p * 64 + wv * 16 + sr) * (long)K + k0 + ssw * 8,
                         nbuf + (p * 64 + wv * 16) * 32);
#pragma unroll
            for (int p = 0; p < BN / 64; p++)
                gl_lds16(Bt + (nbase + p * 64 + wv * 16 + sr) * (long)K + k0 + ssw * 8,
                         nbuf + 128 * 32 + (p * 64 + wv * 16) * 32);
        }
        short8 af[4], bfr[NW];
#pragma unroll
        for (int m = 0; m < 4; m++)
            af[m] = *(const short8*)(cbuf + (wr * 64 + m * 16 + r) * 32 + ((g ^ cxr) * 8));
#pragma unroll
        for (int n = 0; n < NW; n++)
            bfr[n] = *(const short8*)(cbuf + 128 * 32 + (wc * (BN / 2) + n * 16 + r) * 32 + ((g ^ cxr) * 8));
#pragma unroll
        for (int m = 0; m < 4; m++)
#pragma unroll
            for (int n = 0; n < NW; n++) acc[m][n] = MFMA16(af[m], bfr[n], acc[m][n]);
        __syncthreads();                               // vmcnt(0): buf^1 ready
    }

    // ---- epilogue: two 64-row passes through LDS, coalesced fused stores
    const int tr = tid >> 2, seg = tid & 3;
#pragma unroll 1
    for (int half = 0; half < 2; half++) {
        __syncthreads();
        if (wr == half) {
#pragma unroll
            for (int m = 0; m < 4; m++)
#pragma unroll
                for (int n = 0; n < NW; n++)
#pragma unroll
                    for (int i = 0; i < 4; i++)
                        st[(m * 16 + g * 4 + i) * STN + wc * (BN / 2) + n * 16 + r] = acc[m][n][i];
        }
        __syncthreads();
        const long row = mbase + half * 64 + tr;
        if constexpr (BN == 128) {
            const long cb = nbase + seg * 32;
            if constexpr (MODE == 1 || MODE == 3) {
                const float qs = (MODE == 1 && nbase < 768) ? 0.18033688011112042f : 1.0f;
                unsigned short* op = (unsigned short*)Out + row * N + cb;
#pragma unroll
                for (int u2 = 0; u2 < 4; u2++) {
                    float4 a = *(const float4*)(st + tr * STN + seg * 32 + u2 * 8);
                    float4 b = *(const float4*)(st + tr * STN + seg * 32 + u2 * 8 + 4);
                    float4 ba = ((const float4*)bias)[(cb >> 2) + u2 * 2];
                    float4 bb = ((const float4*)bias)[(cb >> 2) + u2 * 2 + 1];
                    a.x += ba.x; a.y += ba.y; a.z += ba.z; a.w += ba.w;
                    b.x += bb.x; b.y += bb.y; b.z += bb.z; b.w += bb.w;
                    if constexpr (MODE == 1) {
                        a.x *= qs; a.y *= qs; a.z *= qs; a.w *= qs;
                        b.x *= qs; b.y *= qs; b.z *= qs; b.w *= qs;
                    } else {
                        a.x = gelu_f(a.x); a.y = gelu_f(a.y); a.z = gelu_f(a.z); a.w = gelu_f(a.w);
                        b.x = gelu_f(b.x); b.y = gelu_f(b.y); b.z = gelu_f(b.z); b.w = gelu_f(b.w);
                    }
                    uint4 w;
                    w.x = cvt_pk_bf16(a.x, a.y);
                    w.y = cvt_pk_bf16(a.z, a.w);
                    w.z = cvt_pk_bf16(b.x, b.y);
                    w.w = cvt_pk_bf16(b.z, b.w);
                    *(uint4*)(op + u2 * 8) = w;
                }
            } else {
                float* op = (float*)Out + row * N + cb;
                const float* rp = resid + row * N + cb;
#pragma unroll
                for (int u = 0; u < 8; u++) {
                    float4 a = *(const float4*)(st + tr * STN + seg * 32 + u * 4);
                    float4 ba = ((const float4*)bias)[(cb >> 2) + u];
                    float4 rr = ((const float4*)rp)[u];
                    a.x += ba.x + rr.x; a.y += ba.y + rr.y;
                    a.z += ba.z + rr.z; a.w += ba.w + rr.w;
                    ((float4*)op)[u] = a;
                }
            }
        } else {
            // BN == 64: only the fp32 + resid modes (proj / fc2)
            const long cb = nbase + seg * 16;
            float* op = (float*)Out + row * N + cb;
            const float* rp = resid + row * N + cb;
#pragma unroll
            for (int u = 0; u < 4; u++) {
                float4 a = *(const float4*)(st + tr * STN + seg * 16 + u * 4);
                float4 ba = ((const float4*)bias)[(cb >> 2) + u];
                float4 rr = ((const float4*)rp)[u];
                a.x += ba.x + rr.x; a.y += ba.y + rr.y;
                a.z += ba.z + rr.z; a.w += ba.w + rr.w;
                ((float4*)op)[u] = a;
            }
        }
    }
}

// ---------------------------------------------------------------------------
// V transpose: qkv[b][t][1536 + h*64 + d] -> vT[bh][d][t]   (bf16, linear)
// ---------------------------------------------------------------------------
__global__ __launch_bounds__(256)
void vtrans(const unsigned short* __restrict__ qkv, unsigned short* __restrict__ vT) {
    const int t0 = blockIdx.x * 64;
    const int bh = blockIdx.y;
    const int b = bh / 12, h = bh % 12;
    __shared__ unsigned short tl[64 * 72];
    const int tid = threadIdx.x;
#pragma unroll
    for (int p = 0; p < 2; p++) {
        int idx = p * 256 + tid;
        int row = idx >> 3, blk = idx & 7;
        int sb = (blk + row) % 9;
        *(u16x8*)(tl + row * 72 + sb * 8) =
            *(const u16x8*)(qkv + ((long)(b * 2048 + t0 + row)) * 2304 + 1536 + h * 64 + blk * 8);
    }
    __syncthreads();
#pragma unroll
    for (int p = 0; p < 2; p++) {
        int idx = p * 256 + tid;
        int d = idx >> 3, tc = (idx & 7) * 8;
        u16x8 v;
#pragma unroll
        for (int j = 0; j < 8; j++) {
            int t = tc + j;
            int sb = ((d >> 3) + t) % 9;
            v[j] = tl[t * 72 + sb * 8 + (d & 7)];
        }
        *(u16x8*)(vT + ((long)(bh * 64 + d)) * 2048 + t0 + tc) = v;
    }
}

// ---------------------------------------------------------------------------
// Flash attention fwd (causal), exp2 domain (q pre-scaled by 0.125*log2e).
// Block = one (b,h) x a PAIR of q-tiles (qt, 31-qt): uniform 33 k-tiles/block.
// K/V double-buffered: stage kt+1 while computing kt (one barrier per tile).
// ---------------------------------------------------------------------------
__global__ __launch_bounds__(256)
void attn_fwd(const unsigned short* __restrict__ qkv, const unsigned short* __restrict__ vT,
              unsigned short* __restrict__ y) {
    const int pair = blockIdx.x;                 // 0..15
    const int bh = blockIdx.y;
    const int b = bh / 12, h = bh % 12;
    __shared__ unsigned short Kl[2 * 64 * 64], Vl[2 * 64 * 64], Pl[64 * 72];
    const int tid = threadIdx.x;
    const int wv = tid >> 6, ln = tid & 63;
    const int g = ln >> 4, r = ln & 15;
    const int lr = ln >> 3, l8 = ln & 7;
    const int sw = l8 ^ lr;                      // staging chunk swizzle
    const int rx = r & 7;
    const f32x4 zero = {0.f, 0.f, 0.f, 0.f};

#pragma unroll 1
    for (int qi = 0; qi < 2; qi++) {
        const int qt = qi ? (31 - pair) : pair;
        const int q0 = qt * 64;
        const int q = wv * 16 + r;               // q-local row this lane owns
        const long qoff = ((long)(b * 2048 + q0 + q)) * 2304 + h * 64;
        short8 bq0 = *(const short8*)(qkv + qoff + g * 8);
        short8 bq1 = *(const short8*)(qkv + qoff + 32 + g * 8);

        float mrow = -1e30f, lrow = 0.0f;
        f32x4 oacc[4];
#pragma unroll
        for (int f = 0; f < 4; f++) oacc[f] = zero;

        // prologue: stage kt=0 into buf 0
#pragma unroll
        for (int p = 0; p < 2; p++) {
            const int row = wv * 8 + p * 32 + lr;
            gl_lds16(qkv + ((long)(b * 2048 + row)) * 2304 + 768 + h * 64 + sw * 8,
                     (char*)Kl + (wv * 8 + p * 32) * 128);
            gl_lds16(vT + ((long)(bh * 64 + row)) * 2048 + sw * 8,
                     (char*)Vl + (wv * 8 + p * 32) * 128);
        }
        __syncthreads();

        for (int kt = 0; kt <= qt; ++kt) {
            const unsigned short* Kb = Kl + (kt & 1) * 4096;
            const unsigned short* Vb = Vl + (kt & 1) * 4096;
            if (kt < qt) {                       // issue next-tile loads first
                char* Kn = (char*)Kl + ((kt + 1) & 1) * 8192;
                char* Vn = (char*)Vl + ((kt + 1) & 1) * 8192;
#pragma unroll
                for (int p = 0; p < 2; p++) {
                    const int row = wv * 8 + p * 32 + lr;
                    gl_lds16(qkv + ((long)(b * 2048 + (kt + 1) * 64 + row)) * 2304 + 768 + h * 64 + sw * 8,
                             Kn + (wv * 8 + p * 32) * 128);
                    gl_lds16(vT + ((long)(bh * 64 + row)) * 2048 + (kt + 1) * 64 + sw * 8,
                             Vn + (wv * 8 + p * 32) * 128);
                }
            }

            f32x4 s[4];
#pragma unroll
            for (int kf = 0; kf < 4; kf++) {
                short8 a0 = *(const short8*)(Kb + (kf * 16 + r) * 64 + (g ^ rx) * 8);
                short8 a1 = *(const short8*)(Kb + (kf * 16 + r) * 64 + ((g + 4) ^ rx) * 8);
                s[kf] = MFMA16(a0, bq0, zero);
                s[kf] = MFMA16(a1, bq1, s[kf]);
            }
            if (kt == qt) {   // diagonal tile: mask k_local > q_local
#pragma unroll
                for (int kf = 0; kf < 4; kf++)
#pragma unroll
                    for (int i = 0; i < 4; i++)
                        if (kf * 16 + g * 4 + i > q) s[kf][i] = -1e30f;
            }
            // ---- online softmax (log2 domain), defer-max
            float tmax = -1e30f;
#pragma unroll
            for (int kf = 0; kf < 4; kf++)
#pragma unroll
                for (int i = 0; i < 4; i++) tmax = fmaxf(tmax, s[kf][i]);
            tmax = fmaxf(tmax, __shfl_xor(tmax, 16));
            tmax = fmaxf(tmax, __shfl_xor(tmax, 32));
            if (__any(tmax > mrow + 6.0f)) {     // rescale only on real growth
                const float mnew = fmaxf(mrow, tmax);
                const float rs = __builtin_amdgcn_exp2f(mrow - mnew);
                lrow *= rs;
#pragma unroll
                for (int f = 0; f < 4; f++) oacc[f] *= rs;
                mrow = mnew;
            }
            float pv[4][4];
            float psum = 0.f;
#pragma unroll
            for (int kf = 0; kf < 4; kf++)
#pragma unroll
                for (int i = 0; i < 4; i++) {
                    pv[kf][i] = __builtin_amdgcn_exp2f(s[kf][i] - mrow);
                    psum += pv[kf][i];
                }
            psum += __shfl_xor(psum, 16);
            psum += __shfl_xor(psum, 32);
            lrow += psum;

            // ---- P^T -> LDS (wave-local rows), packed via v_cvt_pk_bf16_f32
#pragma unroll
            for (int kf = 0; kf < 4; kf++) {
                uint2 w;
                w.x = cvt_pk_bf16(pv[kf][0], pv[kf][1]);
                w.y = cvt_pk_bf16(pv[kf][2], pv[kf][3]);
                *(uint2*)(Pl + q * 72 + kf * 16 + g * 4) = w;
            }
            short8 pb0 = *(const short8*)(Pl + q * 72 + g * 8);
            short8 pb1 = *(const short8*)(Pl + q * 72 + 32 + g * 8);
#pragma unroll
            for (int f = 0; f < 4; f++) {
                short8 va0 = *(const short8*)(Vb + (f * 16 + r) * 64 + (g ^ rx) * 8);
                short8 va1 = *(const short8*)(Vb + (f * 16 + r) * 64 + ((g + 4) ^ rx) * 8);
                oacc[f] = MFMA16(va0, pb0, oacc[f]);
                oacc[f] = MFMA16(va1, pb1, oacc[f]);
            }
            __syncthreads();                     // vmcnt(0): next K/V buf ready
        }

        // ---- epilogue: O^T frags -> LDS (reuse Pl) -> coalesced global
        const float inv = 1.0f / lrow;
#pragma unroll
        for (int f = 0; f < 4; f++) {
            uint2 w;
            w.x = cvt_pk_bf16(oacc[f][0] * inv, oacc[f][1] * inv);
            w.y = cvt_pk_bf16(oacc[f][2] * inv, oacc[f][3] * inv);
            *(uint2*)(Pl + q * 72 + f * 16 + g * 4) = w;
        }
        __syncthreads();
#pragma unroll
        for (int p = 0; p < 2; p++) {
            int idx = p * 256 + tid;
            int row = idx >> 3, cc = (idx & 7) * 8;
            *(u16x8*)(y + ((long)(b * 2048 + q0 + row)) * 768 + h * 64 + cc) =
                *(const u16x8*)(Pl + row * 72 + cc);
        }
        __syncthreads();                         // Pl/bufs safe to reuse in qi=1
    }
}

// ---------------------------------------------------------------------------
extern "C" void kernel_launch(void* const* d_in, const int* in_sizes, int n_in,
                              void* d_out, int out_size, void* d_ws, size_t ws_size,
                              hipStream_t stream) {
    const float* x      = (const float*)d_in[0];
    const float* ln1_g  = (const float*)d_in[1];
    const float* ln1_b  = (const float*)d_in[2];
    const float* W_attn = (const float*)d_in[3];
    const float* b_attn = (const float*)d_in[4];
    const float* W_proj = (const float*)d_in[5];
    const float* b_proj = (const float*)d_in[6];
    const float* ln2_g  = (const float*)d_in[7];
    const float* ln2_b  = (const float*)d_in[8];
    const float* W_fc   = (const float*)d_in[9];
    const float* b_fc   = (const float*)d_in[10];
    const float* W_fc2  = (const float*)d_in[11];
    const float* b_fc2  = (const float*)d_in[12];

    char* ws = (char*)d_ws;
    size_t off = 0;
    auto alloc = [&](size_t bytes) -> char* {
        char* p = ws + off;
        off += (bytes + 255) & ~(size_t)255;
        return p;
    };
    unsigned short* WtA  = (unsigned short*)alloc((size_t)2304 * 768 * 2);
    unsigned short* WtP  = (unsigned short*)alloc((size_t)768 * 768 * 2);
    unsigned short* WtF  = (unsigned short*)alloc((size_t)3072 * 768 * 2);
    unsigned short* WtF2 = (unsigned short*)alloc((size_t)768 * 3072 * 2);
    unsigned short* bigA = (unsigned short*)alloc((size_t)8192 * 3072 * 2); // qkv, then gelu(fc)
    float*          x1   = (float*)alloc((size_t)8192 * 768 * 4);
    unsigned short* bufD = (unsigned short*)alloc((size_t)8192 * 768 * 2);  // h_ln / y / h_ln2
    unsigned short* vT   = (unsigned short*)alloc((size_t)48 * 64 * 2048 * 2);

    // weights -> bf16 transposed
    wtrans<<<dim3(72, 24), dim3(32, 8), 0, stream>>>(W_attn, WtA, 768, 2304);
    wtrans<<<dim3(24, 24), dim3(32, 8), 0, stream>>>(W_proj, WtP, 768, 768);
    wtrans<<<dim3(96, 24), dim3(32, 8), 0, stream>>>(W_fc, WtF, 768, 3072);
    wtrans<<<dim3(24, 96), dim3(32, 8), 0, stream>>>(W_fc2, WtF2, 3072, 768);
    // LN1: x -> bufD (bf16)
    ln_fwd<<<2048, 256, 0, stream>>>(x, ln1_g, ln1_b, bufD);
    // QKV: bufD @ WtA^T -> bigA (bf16, q scaled 0.125*log2e for exp2-domain softmax)
    gemm_bt<1, 128><<<dim3(64, 18), 256, 0, stream>>>(bufD, WtA, b_attn, nullptr, bigA, 8192, 2304, 768);
    // V transpose
    vtrans<<<dim3(32, 48), 256, 0, stream>>>(bigA, vT);
    // attention -> bufD (= y, bf16); paired q-tiles for uniform work
    attn_fwd<<<dim3(16, 48), 256, 0, stream>>>(bigA, vT, bufD);
    // proj: y @ WtP^T + b + x -> x1 (fp32)   [BN=64 -> 768 blocks]
    gemm_bt<2, 64><<<dim3(64, 12), 256, 0, stream>>>(bufD, WtP, b_proj, x, x1, 8192, 768, 768);
    // LN2: x1 -> bufD (bf16)
    ln_fwd<<<2048, 256, 0, stream>>>(x1, ln2_g, ln2_b, bufD);
    // FC + GELU: bufD @ WtF^T -> bigA (bf16)
    gemm_bt<3, 128><<<dim3(64, 24), 256, 0, stream>>>(bufD, WtF, b_fc, nullptr, bigA, 8192, 3072, 768);
    // FC2: bigA @ WtF2^T + b + x1 -> d_out (fp32)   [BN=64 -> 768 blocks]
    gemm_bt<4, 64><<<dim3(64, 12), 256, 0, stream>>>(bigA, WtF2, b_fc2, x1, (float*)d_out, 8192, 768, 3072);
}

// Round 7
// 286.303 us; speedup vs baseline: 1.1813x; 1.0209x over previous
//
#include <hip/hip_runtime.h>
#include <hip/hip_bf16.h>

typedef __attribute__((ext_vector_type(8))) short short8;     // 8 bf16 (MFMA frag)
typedef __attribute__((ext_vector_type(4))) float f32x4;      // MFMA acc frag
typedef __attribute__((ext_vector_type(8))) unsigned short u16x8;
typedef __attribute__((ext_vector_type(4))) unsigned short u16x4;

#define MFMA16(A, B, C) __builtin_amdgcn_mfma_f32_16x16x32_bf16(A, B, C, 0, 0, 0)

static __device__ __forceinline__ unsigned short f2bf(float f) {
    unsigned int u = __builtin_bit_cast(unsigned int, f);
    u += 0x7FFF + ((u >> 16) & 1);   // RNE
    return (unsigned short)(u >> 16);
}

static __device__ __forceinline__ unsigned int cvt_pk_bf16(float a, float b) {
    unsigned int r;
    asm("v_cvt_pk_bf16_f32 %0, %1, %2" : "=v"(r) : "v"(a), "v"(b));
    return r;
}

// fast GELU: 0.5v(1+tanh(c(v+0.044715v^3))) == v * rcp(1 + exp2(-(k1*v + k2*v^3)))
static __device__ __forceinline__ float gelu_f(float v) {
    const float k1 = 2.3022077646f;   // 2*log2(e)*sqrt(2/pi)
    const float k2 = 0.1029432207f;   // k1*0.044715
    float t = __builtin_amdgcn_exp2f(-(k1 * v + k2 * v * v * v));
    return v * __builtin_amdgcn_rcpf(1.0f + t);
}

typedef const __attribute__((address_space(1))) unsigned int* gas_t;
typedef __attribute__((address_space(3))) unsigned int* las_t;
static __device__ __forceinline__ void gl_lds16(const void* g, void* l) {
    __builtin_amdgcn_global_load_lds((gas_t)g, (las_t)l, 16, 0, 0);
}

// ---------------------------------------------------------------------------
// Weight transpose + cast: W [K][N] fp32  ->  Wt [N][K] bf16
// ---------------------------------------------------------------------------
__global__ void wtrans(const float* __restrict__ W, unsigned short* __restrict__ Wt,
                       int K, int N) {
    __shared__ float tl[32][33];
    const int n0 = blockIdx.x * 32, k0 = blockIdx.y * 32;
    const int tx = threadIdx.x, ty = threadIdx.y;
#pragma unroll
    for (int i = 0; i < 4; i++)
        tl[ty + 8 * i][tx] = W[(long)(k0 + ty + 8 * i) * N + n0 + tx];
    __syncthreads();
#pragma unroll
    for (int i = 0; i < 4; i++)
        Wt[(long)(n0 + ty + 8 * i) * K + k0 + tx] = f2bf(tl[tx][ty + 8 * i]);
}

// ---------------------------------------------------------------------------
// LayerNorm: fp32 [rows][768] -> bf16 [rows][768].  One wave per row.
// ---------------------------------------------------------------------------
__global__ __launch_bounds__(256)
void ln_fwd(const float* __restrict__ x, const float* __restrict__ gw,
            const float* __restrict__ bw, unsigned short* __restrict__ out) {
    const int row = blockIdx.x * 4 + (threadIdx.x >> 6);
    const int ln = threadIdx.x & 63;
    const float4* xr = (const float4*)(x + (long)row * 768);
    float4 v[3];
    float s = 0.f;
#pragma unroll
    for (int j = 0; j < 3; j++) {
        v[j] = xr[ln + 64 * j];
        s += v[j].x + v[j].y + v[j].z + v[j].w;
    }
#pragma unroll
    for (int off = 32; off >= 1; off >>= 1) s += __shfl_xor(s, off);
    const float mean = s * (1.0f / 768.0f);
    float sq = 0.f;
#pragma unroll
    for (int j = 0; j < 3; j++) {
        float a = v[j].x - mean, b = v[j].y - mean, c = v[j].z - mean, d = v[j].w - mean;
        sq += a * a + b * b + c * c + d * d;
    }
#pragma unroll
    for (int off = 32; off >= 1; off >>= 1) sq += __shfl_xor(sq, off);
    const float rstd = rsqrtf(sq * (1.0f / 768.0f) + 1e-5f);
#pragma unroll
    for (int j = 0; j < 3; j++) {
        const int c = ln + 64 * j;
        float4 gg = ((const float4*)gw)[c];
        float4 bb = ((const float4*)bw)[c];
        u16x4 o;
        o[0] = f2bf((v[j].x - mean) * rstd * gg.x + bb.x);
        o[1] = f2bf((v[j].y - mean) * rstd * gg.y + bb.y);
        o[2] = f2bf((v[j].z - mean) * rstd * gg.z + bb.z);
        o[3] = f2bf((v[j].w - mean) * rstd * gg.w + bb.w);
        *(u16x4*)(out + (long)row * 768 + c * 4) = o;
    }
}

// ---------------------------------------------------------------------------
// GEMM  C[M,N] = A[M,K] (bf16) x Bt[N,K]^T (bf16) + bias, fused epilogues.
// 2-phase pipelined mainloop: 128xBN tile, BK=32, double-buffered LDS.
// Chunk swizzle: LDS[row][c] holds global chunk c ^ ((row>>1)&3) -- a 16-lane
// ds_read_b128 phase group then covers 8 distinct 4-bank clusters x 2 lanes
// = 2 addr/bank = conflict-free (r6's g^(r&3) gave only 4 clusters -> 4-way,
// 5.1M conflict cycles).
// Epilogue: acc -> LDS fp32 st (stride 132/68) -> coalesced fused stores.
// MODE 1: qkv  [BN=128]: cols<768 scaled 0.125*log2(e) -> bf16 bigA;
//         cols>=1536 (V) written TRANSPOSED into vT[bh*64+d][t] (+bias).
// MODE 2: proj [BN=64]:  fp32 out = acc + bias + resid
// MODE 3: fc   [BN=128]: bf16 out = gelu(acc + bias)
// MODE 4: fc2  [BN=64]:  fp32 out = acc + bias + resid
// ---------------------------------------------------------------------------
template <int MODE, int BN>
__global__ __launch_bounds__(256)
void gemm_bt(const unsigned short* __restrict__ A, const unsigned short* __restrict__ Bt,
             const float* __restrict__ bias, const float* __restrict__ resid,
             void* __restrict__ Out, unsigned short* __restrict__ vT,
             int M, int N, int K) {
    constexpr int NW = BN / 32;                        // n-frags per wave (2x2 waves)
    constexpr int BUF = (128 + BN) * 32;               // u16 elems per K-tile buffer
    constexpr int STN = (BN == 128) ? 132 : 68;        // epilogue staging stride (fp32)
    constexpr int BYTES_MAIN = 2 * BUF * 2;
    constexpr int BYTES_ST = 64 * STN * 4;
    constexpr int BYTES = BYTES_MAIN > BYTES_ST ? BYTES_MAIN : BYTES_ST;
    __shared__ char smem[BYTES];
    unsigned short* ubase = (unsigned short*)smem;
    float* st = (float*)smem;

    const int tid = threadIdx.x;
    const int wv = tid >> 6, ln = tid & 63;
    const int wr = wv >> 1, wc = wv & 1;
    const int g = ln >> 4, r = ln & 15;
    const int sr = ln >> 2, sc = ln & 3;               // staging row-in-16 / chunk
    const int ssw = sc ^ ((sr >> 1) & 3);              // pre-swizzled source chunk
    const long mbase = (long)blockIdx.x * 128;
    const long nbase = (long)blockIdx.y * BN;

    f32x4 acc[4][NW];
    const f32x4 zero = {0.f, 0.f, 0.f, 0.f};
#pragma unroll
    for (int m = 0; m < 4; m++)
#pragma unroll
        for (int n = 0; n < NW; n++) acc[m][n] = zero;

    const int nt = K >> 5;
    // ---- prologue: stage tile 0 into buf 0
#pragma unroll
    for (int p = 0; p < 2; p++)
        gl_lds16(A + (mbase + p * 64 + wv * 16 + sr) * (long)K + ssw * 8,
                 ubase + (p * 64 + wv * 16) * 32);
#pragma unroll
    for (int p = 0; p < BN / 64; p++)
        gl_lds16(Bt + (nbase + p * 64 + wv * 16 + sr) * (long)K + ssw * 8,
                 ubase + 128 * 32 + (p * 64 + wv * 16) * 32);
    __syncthreads();

    const int cx = (r >> 1) & 3;                       // read-side chunk XOR
    for (int t = 0; t < nt; t++) {
        const unsigned short* cbuf = ubase + (t & 1) * BUF;
        if (t + 1 < nt) {                              // issue next-tile loads first
            unsigned short* nbuf = ubase + ((t + 1) & 1) * BUF;
            const long k0 = (long)(t + 1) << 5;
#pragma unroll
            for (int p = 0; p < 2; p++)
                gl_lds16(A + (mbase + p * 64 + wv * 16 + sr) * (long)K + k0 + ssw * 8,
                         nbuf + (p * 64 + wv * 16) * 32);
#pragma unroll
            for (int p = 0; p < BN / 64; p++)
                gl_lds16(Bt + (nbase + p * 64 + wv * 16 + sr) * (long)K + k0 + ssw * 8,
                         nbuf + 128 * 32 + (p * 64 + wv * 16) * 32);
        }
        short8 af[4], bfr[NW];
#pragma unroll
        for (int m = 0; m < 4; m++)
            af[m] = *(const short8*)(cbuf + (wr * 64 + m * 16 + r) * 32 + ((g ^ cx) * 8));
#pragma unroll
        for (int n = 0; n < NW; n++)
            bfr[n] = *(const short8*)(cbuf + 128 * 32 + (wc * (BN / 2) + n * 16 + r) * 32 + ((g ^ cx) * 8));
#pragma unroll
        for (int m = 0; m < 4; m++)
#pragma unroll
            for (int n = 0; n < NW; n++) acc[m][n] = MFMA16(af[m], bfr[n], acc[m][n]);
        __syncthreads();                               // vmcnt(0): buf^1 ready
    }

    // ---- epilogue: two 64-row passes through LDS, coalesced fused stores
    const int tr = tid >> 2, seg = tid & 3;
#pragma unroll 1
    for (int half = 0; half < 2; half++) {
        __syncthreads();
        if (wr == half) {
#pragma unroll
            for (int m = 0; m < 4; m++)
#pragma unroll
                for (int n = 0; n < NW; n++)
#pragma unroll
                    for (int i = 0; i < 4; i++)
                        st[(m * 16 + g * 4 + i) * STN + wc * (BN / 2) + n * 16 + r] = acc[m][n][i];
        }
        __syncthreads();
        const long row = mbase + half * 64 + tr;
        if constexpr (MODE == 1) {
            if (nbase >= 1536) {
                // V block -> vT[(b*12+h)*64 + d][t], bias fused, transposed read of st
                const int tc = tid & 7;                // t-octet within the 64-row pass
                const int d0 = tid >> 3;               // 0..31
                const long bb = mbase >> 11;           // batch (2048 rows per b)
                const int tg0 = (int)(mbase & 2047) + half * 64 + tc * 8;
#pragma unroll
                for (int it = 0; it < 4; it++) {
                    const int dl = it * 32 + d0;       // 0..127 local col
                    const int h = (int)((nbase - 1536) >> 6) + (dl >> 6);
                    const int dd = dl & 63;
                    const float bc = bias[nbase + dl];
                    u16x8 o;
#pragma unroll
                    for (int j = 0; j < 8; j++)
                        o[j] = f2bf(st[(tc * 8 + j) * STN + dl] + bc);
                    *(u16x8*)(vT + ((bb * 12 + h) * 64 + dd) * 2048 + tg0) = o;
                }
            } else {
                const float qs = (nbase < 768) ? 0.18033688011112042f : 1.0f;
                const long cb = nbase + seg * 32;
                unsigned short* op = (unsigned short*)Out + row * N + cb;
#pragma unroll
                for (int u2 = 0; u2 < 4; u2++) {
                    float4 a = *(const float4*)(st + tr * STN + seg * 32 + u2 * 8);
                    float4 b = *(const float4*)(st + tr * STN + seg * 32 + u2 * 8 + 4);
                    float4 ba = ((const float4*)bias)[(cb >> 2) + u2 * 2];
                    float4 bb2 = ((const float4*)bias)[(cb >> 2) + u2 * 2 + 1];
                    a.x = (a.x + ba.x) * qs; a.y = (a.y + ba.y) * qs;
                    a.z = (a.z + ba.z) * qs; a.w = (a.w + ba.w) * qs;
                    b.x = (b.x + bb2.x) * qs; b.y = (b.y + bb2.y) * qs;
                    b.z = (b.z + bb2.z) * qs; b.w = (b.w + bb2.w) * qs;
                    uint4 w;
                    w.x = cvt_pk_bf16(a.x, a.y);
                    w.y = cvt_pk_bf16(a.z, a.w);
                    w.z = cvt_pk_bf16(b.x, b.y);
                    w.w = cvt_pk_bf16(b.z, b.w);
                    *(uint4*)(op + u2 * 8) = w;
                }
            }
        } else if constexpr (MODE == 3) {
            const long cb = nbase + seg * 32;
            unsigned short* op = (unsigned short*)Out + row * N + cb;
#pragma unroll
            for (int u2 = 0; u2 < 4; u2++) {
                float4 a = *(const float4*)(st + tr * STN + seg * 32 + u2 * 8);
                float4 b = *(const float4*)(st + tr * STN + seg * 32 + u2 * 8 + 4);
                float4 ba = ((const float4*)bias)[(cb >> 2) + u2 * 2];
                float4 bb2 = ((const float4*)bias)[(cb >> 2) + u2 * 2 + 1];
                a.x = gelu_f(a.x + ba.x); a.y = gelu_f(a.y + ba.y);
                a.z = gelu_f(a.z + ba.z); a.w = gelu_f(a.w + ba.w);
                b.x = gelu_f(b.x + bb2.x); b.y = gelu_f(b.y + bb2.y);
                b.z = gelu_f(b.z + bb2.z); b.w = gelu_f(b.w + bb2.w);
                uint4 w;
                w.x = cvt_pk_bf16(a.x, a.y);
                w.y = cvt_pk_bf16(a.z, a.w);
                w.z = cvt_pk_bf16(b.x, b.y);
                w.w = cvt_pk_bf16(b.z, b.w);
                *(uint4*)(op + u2 * 8) = w;
            }
        } else {
            // BN == 64 fp32 + resid modes (proj / fc2)
            const long cb = nbase + seg * 16;
            float* op = (float*)Out + row * N + cb;
            const float* rp = resid + row * N + cb;
#pragma unroll
            for (int u = 0; u < 4; u++) {
                float4 a = *(const float4*)(st + tr * STN + seg * 16 + u * 4);
                float4 ba = ((const float4*)bias)[(cb >> 2) + u];
                float4 rr = ((const float4*)rp)[u];
                a.x += ba.x + rr.x; a.y += ba.y + rr.y;
                a.z += ba.z + rr.z; a.w += ba.w + rr.w;
                ((float4*)op)[u] = a;
            }
        }
    }
}

// ---------------------------------------------------------------------------
// Flash attention fwd (causal), exp2 domain (q pre-scaled by 0.125*log2e).
// Block = one (b,h) x a PAIR of q-tiles (qt, 31-qt): uniform 33 k-tiles/block.
// K/V double-buffered: stage kt+1 while computing kt (one barrier per tile).
// ---------------------------------------------------------------------------
__global__ __launch_bounds__(256)
void attn_fwd(const unsigned short* __restrict__ qkv, const unsigned short* __restrict__ vT,
              unsigned short* __restrict__ y) {
    const int pair = blockIdx.x;                 // 0..15
    const int bh = blockIdx.y;
    const int b = bh / 12, h = bh % 12;
    __shared__ unsigned short Kl[2 * 64 * 64], Vl[2 * 64 * 64], Pl[64 * 72];
    const int tid = threadIdx.x;
    const int wv = tid >> 6, ln = tid & 63;
    const int g = ln >> 4, r = ln & 15;
    const int lr = ln >> 3, l8 = ln & 7;
    const int sw = l8 ^ lr;                      // staging chunk swizzle
    const int rx = r & 7;
    const f32x4 zero = {0.f, 0.f, 0.f, 0.f};

#pragma unroll 1
    for (int qi = 0; qi < 2; qi++) {
        const int qt = qi ? (31 - pair) : pair;
        const int q0 = qt * 64;
        const int q = wv * 16 + r;               // q-local row this lane owns
        const long qoff = ((long)(b * 2048 + q0 + q)) * 2304 + h * 64;
        short8 bq0 = *(const short8*)(qkv + qoff + g * 8);
        short8 bq1 = *(const short8*)(qkv + qoff + 32 + g * 8);

        float mrow = -1e30f, lrow = 0.0f;
        f32x4 oacc[4];
#pragma unroll
        for (int f = 0; f < 4; f++) oacc[f] = zero;

        // prologue: stage kt=0 into buf 0
#pragma unroll
        for (int p = 0; p < 2; p++) {
            const int row = wv * 8 + p * 32 + lr;
            gl_lds16(qkv + ((long)(b * 2048 + row)) * 2304 + 768 + h * 64 + sw * 8,
                     (char*)Kl + (wv * 8 + p * 32) * 128);
            gl_lds16(vT + ((long)(bh * 64 + row)) * 2048 + sw * 8,
                     (char*)Vl + (wv * 8 + p * 32) * 128);
        }
        __syncthreads();

        for (int kt = 0; kt <= qt; ++kt) {
            const unsigned short* Kb = Kl + (kt & 1) * 4096;
            const unsigned short* Vb = Vl + (kt & 1) * 4096;
            if (kt < qt) {                       // issue next-tile loads first
                char* Kn = (char*)Kl + ((kt + 1) & 1) * 8192;
                char* Vn = (char*)Vl + ((kt + 1) & 1) * 8192;
#pragma unroll
                for (int p = 0; p < 2; p++) {
                    const int row = wv * 8 + p * 32 + lr;
                    gl_lds16(qkv + ((long)(b * 2048 + (kt + 1) * 64 + row)) * 2304 + 768 + h * 64 + sw * 8,
                             Kn + (wv * 8 + p * 32) * 128);
                    gl_lds16(vT + ((long)(bh * 64 + row)) * 2048 + (kt + 1) * 64 + sw * 8,
                             Vn + (wv * 8 + p * 32) * 128);
                }
            }

            f32x4 s[4];
#pragma unroll
            for (int kf = 0; kf < 4; kf++) {
                short8 a0 = *(const short8*)(Kb + (kf * 16 + r) * 64 + (g ^ rx) * 8);
                short8 a1 = *(const short8*)(Kb + (kf * 16 + r) * 64 + ((g + 4) ^ rx) * 8);
                s[kf] = MFMA16(a0, bq0, zero);
                s[kf] = MFMA16(a1, bq1, s[kf]);
            }
            if (kt == qt) {   // diagonal tile: mask k_local > q_local
#pragma unroll
                for (int kf = 0; kf < 4; kf++)
#pragma unroll
                    for (int i = 0; i < 4; i++)
                        if (kf * 16 + g * 4 + i > q) s[kf][i] = -1e30f;
            }
            // ---- online softmax (log2 domain), defer-max
            float tmax = -1e30f;
#pragma unroll
            for (int kf = 0; kf < 4; kf++)
#pragma unroll
                for (int i = 0; i < 4; i++) tmax = fmaxf(tmax, s[kf][i]);
            tmax = fmaxf(tmax, __shfl_xor(tmax, 16));
            tmax = fmaxf(tmax, __shfl_xor(tmax, 32));
            if (__any(tmax > mrow + 6.0f)) {     // rescale only on real growth
                const float mnew = fmaxf(mrow, tmax);
                const float rs = __builtin_amdgcn_exp2f(mrow - mnew);
                lrow *= rs;
#pragma unroll
                for (int f = 0; f < 4; f++) oacc[f] *= rs;
                mrow = mnew;
            }
            float pv[4][4];
            float psum = 0.f;
#pragma unroll
            for (int kf = 0; kf < 4; kf++)
#pragma unroll
                for (int i = 0; i < 4; i++) {
                    pv[kf][i] = __builtin_amdgcn_exp2f(s[kf][i] - mrow);
                    psum += pv[kf][i];
                }
            psum += __shfl_xor(psum, 16);
            psum += __shfl_xor(psum, 32);
            lrow += psum;

            // ---- P^T -> LDS (wave-local rows), packed via v_cvt_pk_bf16_f32
#pragma unroll
            for (int kf = 0; kf < 4; kf++) {
                uint2 w;
                w.x = cvt_pk_bf16(pv[kf][0], pv[kf][1]);
                w.y = cvt_pk_bf16(pv[kf][2], pv[kf][3]);
                *(uint2*)(Pl + q * 72 + kf * 16 + g * 4) = w;
            }
            short8 pb0 = *(const short8*)(Pl + q * 72 + g * 8);
            short8 pb1 = *(const short8*)(Pl + q * 72 + 32 + g * 8);
#pragma unroll
            for (int f = 0; f < 4; f++) {
                short8 va0 = *(const short8*)(Vb + (f * 16 + r) * 64 + (g ^ rx) * 8);
                short8 va1 = *(const short8*)(Vb + (f * 16 + r) * 64 + ((g + 4) ^ rx) * 8);
                oacc[f] = MFMA16(va0, pb0, oacc[f]);
                oacc[f] = MFMA16(va1, pb1, oacc[f]);
            }
            __syncthreads();                     // vmcnt(0): next K/V buf ready
        }

        // ---- epilogue: O^T frags -> LDS (reuse Pl) -> coalesced global
        const float inv = 1.0f / lrow;
#pragma unroll
        for (int f = 0; f < 4; f++) {
            uint2 w;
            w.x = cvt_pk_bf16(oacc[f][0] * inv, oacc[f][1] * inv);
            w.y = cvt_pk_bf16(oacc[f][2] * inv, oacc[f][3] * inv);
            *(uint2*)(Pl + q * 72 + f * 16 + g * 4) = w;
        }
        __syncthreads();
#pragma unroll
        for (int p = 0; p < 2; p++) {
            int idx = p * 256 + tid;
            int row = idx >> 3, cc = (idx & 7) * 8;
            *(u16x8*)(y + ((long)(b * 2048 + q0 + row)) * 768 + h * 64 + cc) =
                *(const u16x8*)(Pl + row * 72 + cc);
        }
        __syncthreads();                         // Pl/bufs safe to reuse in qi=1
    }
}

// ---------------------------------------------------------------------------
extern "C" void kernel_launch(void* const* d_in, const int* in_sizes, int n_in,
                              void* d_out, int out_size, void* d_ws, size_t ws_size,
                              hipStream_t stream) {
    const float* x      = (const float*)d_in[0];
    const float* ln1_g  = (const float*)d_in[1];
    const float* ln1_b  = (const float*)d_in[2];
    const float* W_attn = (const float*)d_in[3];
    const float* b_attn = (const float*)d_in[4];
    const float* W_proj = (const float*)d_in[5];
    const float* b_proj = (const float*)d_in[6];
    const float* ln2_g  = (const float*)d_in[7];
    const float* ln2_b  = (const float*)d_in[8];
    const float* W_fc   = (const float*)d_in[9];
    const float* b_fc   = (const float*)d_in[10];
    const float* W_fc2  = (const float*)d_in[11];
    const float* b_fc2  = (const float*)d_in[12];

    char* ws = (char*)d_ws;
    size_t off = 0;
    auto alloc = [&](size_t bytes) -> char* {
        char* p = ws + off;
        off += (bytes + 255) & ~(size_t)255;
        return p;
    };
    unsigned short* WtA  = (unsigned short*)alloc((size_t)2304 * 768 * 2);
    unsigned short* WtP  = (unsigned short*)alloc((size_t)768 * 768 * 2);
    unsigned short* WtF  = (unsigned short*)alloc((size_t)3072 * 768 * 2);
    unsigned short* WtF2 = (unsigned short*)alloc((size_t)768 * 3072 * 2);
    unsigned short* bigA = (unsigned short*)alloc((size_t)8192 * 3072 * 2); // qkv(q,k), then gelu(fc)
    float*          x1   = (float*)alloc((size_t)8192 * 768 * 4);
    unsigned short* bufD = (unsigned short*)alloc((size_t)8192 * 768 * 2);  // h_ln / y / h_ln2
    unsigned short* vT   = (unsigned short*)alloc((size_t)48 * 64 * 2048 * 2);

    // weights -> bf16 transposed
    wtrans<<<dim3(72, 24), dim3(32, 8), 0, stream>>>(W_attn, WtA, 768, 2304);
    wtrans<<<dim3(24, 24), dim3(32, 8), 0, stream>>>(W_proj, WtP, 768, 768);
    wtrans<<<dim3(96, 24), dim3(32, 8), 0, stream>>>(W_fc, WtF, 768, 3072);
    wtrans<<<dim3(24, 96), dim3(32, 8), 0, stream>>>(W_fc2, WtF2, 3072, 768);
    // LN1: x -> bufD (bf16)
    ln_fwd<<<2048, 256, 0, stream>>>(x, ln1_g, ln1_b, bufD);
    // QKV: bufD @ WtA^T -> bigA (q scaled 0.125*log2e); V written transposed into vT
    gemm_bt<1, 128><<<dim3(64, 18), 256, 0, stream>>>(bufD, WtA, b_attn, nullptr, bigA, vT, 8192, 2304, 768);
    // attention -> bufD (= y, bf16); paired q-tiles for uniform work
    attn_fwd<<<dim3(16, 48), 256, 0, stream>>>(bigA, vT, bufD);
    // proj: y @ WtP^T + b + x -> x1 (fp32)   [BN=64 -> 768 blocks]
    gemm_bt<2, 64><<<dim3(64, 12), 256, 0, stream>>>(bufD, WtP, b_proj, x, x1, nullptr, 8192, 768, 768);
    // LN2: x1 -> bufD (bf16)
    ln_fwd<<<2048, 256, 0, stream>>>(x1, ln2_g, ln2_b, bufD);
    // FC + GELU: bufD @ WtF^T -> bigA (bf16)
    gemm_bt<3, 128><<<dim3(64, 24), 256, 0, stream>>>(bufD, WtF, b_fc, nullptr, bigA, nullptr, 8192, 3072, 768);
    // FC2: bigA @ WtF2^T + b + x1 -> d_out (fp32)   [BN=64 -> 768 blocks]
    gemm_bt<4, 64><<<dim3(64, 12), 256, 0, stream>>>(bigA, WtF2, b_fc2, x1, (float*)d_out, nullptr, 8192, 768, 3072);
}